// Round 10
// baseline (743.329 us; speedup 1.0000x reference)
//
#include <hip/hip_runtime.h>

// VQ argmin: exact bit-level emulation of numpy fp32 reference:
//   A  = np.sum(flat*flat, axis=1)     (numpy pairwise-sum tree, fp32)
//   M2 = (2*flat) @ emb.T              (BLAS: sequential fp32 fma chain over d)
//   dist = (A - M2) + ee;  argmin_k (first-min ties)
// z_e_x: [B=16, D=256, H=64, W=64] fp32; embedding: [K=1024, D=256] fp32
// out: int32 [65536]
//
// R13: lane->k mapping (the inversion R3-R12 never tried). Every prior
// structure had 64 lanes consuming the SAME 64 er values per d-row; all
// three delivery channels measured as the bottleneck (s_load/K$: R3 66%
// VALU; LDS broadcast: R12 16B/instr -> 6x LDS-pipe oversubscription;
// per-thread GEMM tiles: R9/R10 conflicts/barriers). Now: lane l owns
// k=kb+l -> er row = ONE coalesced global_load_dword (256B/wave, all
// useful); z[n][d] is wave-uniform -> ONE s_load_dwordx8 per row (64B,
// fully consumed). FMA = v_fmac(acc, s_z, v_er): 1 SGPR operand, legal.
// acc[8 n] + running-best(key,k)[8] ~= 50 VGPR -> launch_bounds(256,8):
// 8 waves/SIMD (2x any prior round). Wave sweeps all 16 k-tiles, running
// best in-register -> each n finalized by ONE wave -> direct out[] write,
// no atomics/memset/unpack. Cross-lane argmin: 6-step shfl_xor u64 min,
// key=(order-encoded distbits, k) -> exact first-min ties (per-lane
// strict-< keeps earliest k; u64 min picks lowest k among tied lanes).
// Exact: per-(n,k) fmaf chain over d ascending unchanged; dist=(An-acc)+ee.
// Aux: et+ee+a fused into one prep kernel (772 blocks). 2 launches total.

#define D_DIM  256
#define K_DIM  1024
#define HW     4096
#define N_TOT  65536
#define NW     8                  // n's per wave
#define F32MAX 3.402823466e38f

// ---- fused prep: [0,256) et transpose | [256,768) A | [768,772) ee

__global__ void prep_kernel(const float* __restrict__ z, const float* __restrict__ e,
                            float* __restrict__ eT, float* __restrict__ A,
                            float* __restrict__ ee) {
#pragma clang fp contract(off)
    const int bid = blockIdx.x;
    const int t   = threadIdx.x;

    if (bid < 256) {
        // ---- transpose + fold the exact x2: eT[d][k] = 2*emb[k][d]
        __shared__ float tl[32][33];
        const int k0 = (bid & 31) * 32;
        const int d0 = (bid >> 5) * 32;
        const int tx = t & 31;
        const int ty = t >> 5;          // 0..7
        #pragma unroll
        for (int i = 0; i < 32; i += 8)
            tl[ty + i][tx] = 2.0f * e[(size_t)(k0 + ty + i) * D_DIM + d0 + tx];
        __syncthreads();
        #pragma unroll
        for (int i = 0; i < 32; i += 8)
            eT[(size_t)(d0 + ty + i) * K_DIM + k0 + tx] = tl[tx][ty + i];
    } else if (bid < 768) {
        // ---- A = numpy pairwise ||z_n||^2: 2 threads/n, one 128-half each
        // (independent 8-acc chains; total = s0 + s1). Bitwise-exact.
        const int tt = (bid - 256) * 256 + t;    // 0 .. 2*N_TOT-1
        const int n  = tt >> 1;
        const int h  = tt & 1;
        const int b  = n >> 12;
        const int hw = n & (HW - 1);
        const float* base = z + (size_t)b * D_DIM * HW + hw + (size_t)(h * 128) * HW;
        float r[8];
        #pragma unroll
        for (int j = 0; j < 8; ++j) { float v = base[(size_t)j * HW]; r[j] = v * v; }
        #pragma unroll
        for (int i = 8; i < 128; i += 8) {
            #pragma unroll
            for (int j = 0; j < 8; ++j) {
                float v = base[(size_t)(i + j) * HW];
                r[j] = r[j] + v * v;
            }
        }
        float s = ((r[0] + r[1]) + (r[2] + r[3])) + ((r[4] + r[5]) + (r[6] + r[7]));
        float other = __shfl_xor(s, 1);
        if (h == 0) A[n] = s + other;
    } else {
        // ---- ee = numpy pairwise ||e_k||^2 (two 128-halves of 8 accs)
        const int k = (bid - 768) * 256 + t;
        const float* row = e + (size_t)k * D_DIM;
        float total = 0.0f;
        #pragma unroll
        for (int h = 0; h < 2; ++h) {
            const float* a = row + h * 128;
            float r[8];
            #pragma unroll
            for (int j = 0; j < 8; ++j) { float v = a[j]; r[j] = v * v; }
            #pragma unroll
            for (int i = 8; i < 128; i += 8) {
                #pragma unroll
                for (int j = 0; j < 8; ++j) { float v = a[i + j]; r[j] = r[j] + v * v; }
            }
            float s = ((r[0] + r[1]) + (r[2] + r[3])) + ((r[4] + r[5]) + (r[6] + r[7]));
            total = (h == 0) ? s : (total + s);
        }
        ee[k] = total;
    }
}

// ---- main: wave owns 8 consecutive n (one b, contiguous hw -> z rows are
// 32B-contiguous wave-uniform) x all 1024 k (16 tiles of 64 = one k/lane).
// Per d-row: 1 coalesced er vector load + 1 uniform z scalar load + 8 fmac.

__launch_bounds__(256, 8)
__global__ void vq_kernel(const float* __restrict__ z, const float* __restrict__ eT,
                          const float* __restrict__ A, const float* __restrict__ ee,
                          int* __restrict__ out) {
#pragma clang fp contract(off)
    const int lane = threadIdx.x & 63;
    const int wid  = __builtin_amdgcn_readfirstlane(threadIdx.x >> 6);
    const int gw   = blockIdx.x * 4 + wid;       // 0..8191, wave-uniform
    const int n0   = gw * NW;
    const int b    = n0 >> 12;                   // NW | 4096: never spans b
    const int hw0  = n0 & (HW - 1);
    const float* __restrict__ zrow = z + (size_t)b * D_DIM * HW + hw0;

    // A[n0..n0+7]: wave-uniform scalar loads
    float An[NW];
    #pragma unroll
    for (int i = 0; i < NW; ++i) An[i] = A[n0 + i];

    unsigned int bkey[NW], bk[NW];
    #pragma unroll
    for (int i = 0; i < NW; ++i) { bkey[i] = 0xFFFFFFFFu; bk[i] = 0u; }

    #pragma unroll 1
    for (int kt = 0; kt < 16; ++kt) {
        const int kb = kt * 64;
        const float* __restrict__ ep = eT + kb + lane;   // per-lane k column

        float acc[NW];
        #pragma unroll
        for (int i = 0; i < NW; ++i) acc[i] = 0.0f;

        // d ascending in groups of 8: 8 er vector loads (compiler pipelines
        // via vmcnt) + 8 uniform z rows + 64 fmac. Exact per-(n,k) chain.
        #pragma unroll 1
        for (int d = 0; d < D_DIM; d += 8) {
            float er[8];
            #pragma unroll
            for (int r = 0; r < 8; ++r)
                er[r] = ep[(size_t)(d + r) * K_DIM];
            #pragma unroll
            for (int r = 0; r < 8; ++r) {
                const float* zr = zrow + (size_t)(d + r) * HW;
                #pragma unroll
                for (int i = 0; i < NW; ++i)
                    acc[i] = fmaf(zr[i], er[r], acc[i]);   // s_z * v_er
            }
        }

        // fold tile into running best (per lane, per n). Strict < keeps the
        // earliest tile -> this lane's smallest k among equal dist bits.
        const float eev = ee[kb + lane];
        #pragma unroll
        for (int i = 0; i < NW; ++i) {
            const float dist = (An[i] - acc[i]) + eev;
            unsigned int kb32 = __float_as_uint(dist);
            kb32 ^= (unsigned int)((int)kb32 >> 31) | 0x80000000u;  // total order
            if (kb32 < bkey[i]) { bkey[i] = kb32; bk[i] = (unsigned int)(kb + lane); }
        }
    }

    // cross-lane exact first-min: u64 (key, k) butterfly min over 64 lanes;
    // equal keys resolve to the lowest k. Each n belongs to exactly one
    // wave -> plain store, no atomics.
    #pragma unroll
    for (int i = 0; i < NW; ++i) {
        unsigned long long key =
            ((unsigned long long)bkey[i] << 32) | (unsigned long long)bk[i];
        #pragma unroll
        for (int m = 1; m < 64; m <<= 1) {
            unsigned long long o = __shfl_xor(key, m, 64);
            if (o < key) key = o;
        }
        if (lane == 0) out[n0 + i] = (int)(key & 0xFFFFFFFFull);
    }
}

extern "C" void kernel_launch(void* const* d_in, const int* in_sizes, int n_in,
                              void* d_out, int out_size, void* d_ws, size_t ws_size,
                              hipStream_t stream) {
    const float* z   = (const float*)d_in[0];   // [16,256,64,64]
    const float* emb = (const float*)d_in[1];   // [1024,256]
    int* out = (int*)d_out;                     // [65536] int32

    float* wsEE = (float*)d_ws;                 // 1024
    float* wsA  = wsEE + K_DIM;                 // 65536
    float* wsET = wsA + N_TOT;                  // 262144

    prep_kernel<<<772, 256, 0, stream>>>(z, emb, wsET, wsA, wsEE);
    vq_kernel<<<N_TOT / NW / 4, 256, 0, stream>>>(z, wsET, wsA, wsEE, out);
}

// Round 11
// 694.610 us; speedup vs baseline: 1.0701x; 1.0701x over previous
//
#include <hip/hip_runtime.h>

// VQ argmin: exact bit-level emulation of numpy fp32 reference:
//   A  = np.sum(flat*flat, axis=1)     (numpy pairwise-sum tree, fp32)
//   M2 = (2*flat) @ emb.T              (BLAS: sequential fp32 fma chain over d)
//   dist = (A - M2) + ee;  argmin_k (first-min ties)
// z_e_x: [B=16, D=256, H=64, W=64] fp32; embedding: [K=1024, D=256] fp32
// out: int32 [65536]
//
// R14: R13's lane->k mapping with NW 8->16. R13 measured VALUBusy 50% at
// 8 waves/SIMD: the limiter is er L2 service -- every wave sweeps the full
// 1MB eT, 8192 waves x 1MB = 8GB of L2 traffic (~230-320us at L2 BW),
// saturating independent of occupancy. NW=16 doubles FMA per er load
// (16:1) and halves er L2 traffic to 4GB (~120-160us < VALU issue floor
// ~233us). z row = one s_load_dwordx16 (64B, fully consumed). Grid 4096
// waves = 4 blocks/CU -> proven (256,4)/128-reg budget (acc16+er8+best32
// +temps ~70 VGPR). All else identical to R13: exact fmaf chain
// d-ascending, dist=(An-acc)+ee, per-lane strict-< over kt ascending +
// u64 (distbits,k) butterfly -> exact first-min ties, direct out[] store
// (1 wave per n), fused prep kernel, 2 launches total.

#define D_DIM  256
#define K_DIM  1024
#define HW     4096
#define N_TOT  65536
#define NW     16                 // n's per wave
#define F32MAX 3.402823466e38f

// ---- fused prep: [0,256) et transpose | [256,768) A | [768,772) ee

__global__ void prep_kernel(const float* __restrict__ z, const float* __restrict__ e,
                            float* __restrict__ eT, float* __restrict__ A,
                            float* __restrict__ ee) {
#pragma clang fp contract(off)
    const int bid = blockIdx.x;
    const int t   = threadIdx.x;

    if (bid < 256) {
        // ---- transpose + fold the exact x2: eT[d][k] = 2*emb[k][d]
        __shared__ float tl[32][33];
        const int k0 = (bid & 31) * 32;
        const int d0 = (bid >> 5) * 32;
        const int tx = t & 31;
        const int ty = t >> 5;          // 0..7
        #pragma unroll
        for (int i = 0; i < 32; i += 8)
            tl[ty + i][tx] = 2.0f * e[(size_t)(k0 + ty + i) * D_DIM + d0 + tx];
        __syncthreads();
        #pragma unroll
        for (int i = 0; i < 32; i += 8)
            eT[(size_t)(d0 + ty + i) * K_DIM + k0 + tx] = tl[tx][ty + i];
    } else if (bid < 768) {
        // ---- A = numpy pairwise ||z_n||^2: 2 threads/n, one 128-half each
        // (independent 8-acc chains; total = s0 + s1). Bitwise-exact.
        const int tt = (bid - 256) * 256 + t;    // 0 .. 2*N_TOT-1
        const int n  = tt >> 1;
        const int h  = tt & 1;
        const int b  = n >> 12;
        const int hw = n & (HW - 1);
        const float* base = z + (size_t)b * D_DIM * HW + hw + (size_t)(h * 128) * HW;
        float r[8];
        #pragma unroll
        for (int j = 0; j < 8; ++j) { float v = base[(size_t)j * HW]; r[j] = v * v; }
        #pragma unroll
        for (int i = 8; i < 128; i += 8) {
            #pragma unroll
            for (int j = 0; j < 8; ++j) {
                float v = base[(size_t)(i + j) * HW];
                r[j] = r[j] + v * v;
            }
        }
        float s = ((r[0] + r[1]) + (r[2] + r[3])) + ((r[4] + r[5]) + (r[6] + r[7]));
        float other = __shfl_xor(s, 1);
        if (h == 0) A[n] = s + other;
    } else {
        // ---- ee = numpy pairwise ||e_k||^2 (two 128-halves of 8 accs)
        const int k = (bid - 768) * 256 + t;
        const float* row = e + (size_t)k * D_DIM;
        float total = 0.0f;
        #pragma unroll
        for (int h = 0; h < 2; ++h) {
            const float* a = row + h * 128;
            float r[8];
            #pragma unroll
            for (int j = 0; j < 8; ++j) { float v = a[j]; r[j] = v * v; }
            #pragma unroll
            for (int i = 8; i < 128; i += 8) {
                #pragma unroll
                for (int j = 0; j < 8; ++j) { float v = a[i + j]; r[j] = r[j] + v * v; }
            }
            float s = ((r[0] + r[1]) + (r[2] + r[3])) + ((r[4] + r[5]) + (r[6] + r[7]));
            total = (h == 0) ? s : (total + s);
        }
        ee[k] = total;
    }
}

// ---- main: wave owns 16 consecutive n (one b, contiguous hw -> z rows are
// 64B-contiguous wave-uniform) x all 1024 k (16 tiles of 64 = one k/lane).
// Per d-row: 1 coalesced er vector load (256B, all useful) + 1 uniform
// s_load_dwordx16 (64B, all useful) + 16 v_fmac.

__launch_bounds__(256, 4)
__global__ void vq_kernel(const float* __restrict__ z, const float* __restrict__ eT,
                          const float* __restrict__ A, const float* __restrict__ ee,
                          int* __restrict__ out) {
#pragma clang fp contract(off)
    const int lane = threadIdx.x & 63;
    const int wid  = __builtin_amdgcn_readfirstlane(threadIdx.x >> 6);
    const int gw   = blockIdx.x * 4 + wid;       // 0..4095, wave-uniform
    const int n0   = gw * NW;
    const int b    = n0 >> 12;                   // NW | 4096: never spans b
    const int hw0  = n0 & (HW - 1);
    const float* __restrict__ zrow = z + (size_t)b * D_DIM * HW + hw0;

    // A[n0..n0+15]: wave-uniform scalar loads
    float An[NW];
    #pragma unroll
    for (int i = 0; i < NW; ++i) An[i] = A[n0 + i];

    unsigned int bkey[NW], bk[NW];
    #pragma unroll
    for (int i = 0; i < NW; ++i) { bkey[i] = 0xFFFFFFFFu; bk[i] = 0u; }

    #pragma unroll 1
    for (int kt = 0; kt < 16; ++kt) {
        const int kb = kt * 64;
        const float* __restrict__ ep = eT + kb + lane;   // per-lane k column

        float acc[NW];
        #pragma unroll
        for (int i = 0; i < NW; ++i) acc[i] = 0.0f;

        // d ascending in groups of 8: 8 er vector loads (pipelined via
        // vmcnt) + 8 uniform z rows + 128 fmac. Exact per-(n,k) chain.
        #pragma unroll 1
        for (int d = 0; d < D_DIM; d += 8) {
            float er[8];
            #pragma unroll
            for (int r = 0; r < 8; ++r)
                er[r] = ep[(size_t)(d + r) * K_DIM];
            #pragma unroll
            for (int r = 0; r < 8; ++r) {
                const float* zr = zrow + (size_t)(d + r) * HW;
                #pragma unroll
                for (int i = 0; i < NW; ++i)
                    acc[i] = fmaf(zr[i], er[r], acc[i]);   // s_z * v_er
            }
        }

        // fold tile into running best (per lane, per n). Strict < keeps the
        // earliest tile -> this lane's smallest k among equal dist bits.
        const float eev = ee[kb + lane];
        #pragma unroll
        for (int i = 0; i < NW; ++i) {
            const float dist = (An[i] - acc[i]) + eev;
            unsigned int kb32 = __float_as_uint(dist);
            kb32 ^= (unsigned int)((int)kb32 >> 31) | 0x80000000u;  // total order
            if (kb32 < bkey[i]) { bkey[i] = kb32; bk[i] = (unsigned int)(kb + lane); }
        }
    }

    // cross-lane exact first-min: u64 (key, k) butterfly min over 64 lanes;
    // equal keys resolve to the lowest k. Each n belongs to exactly one
    // wave -> plain store, no atomics.
    #pragma unroll
    for (int i = 0; i < NW; ++i) {
        unsigned long long key =
            ((unsigned long long)bkey[i] << 32) | (unsigned long long)bk[i];
        #pragma unroll
        for (int m = 1; m < 64; m <<= 1) {
            unsigned long long o = __shfl_xor(key, m, 64);
            if (o < key) key = o;
        }
        if (lane == 0) out[n0 + i] = (int)(key & 0xFFFFFFFFull);
    }
}

extern "C" void kernel_launch(void* const* d_in, const int* in_sizes, int n_in,
                              void* d_out, int out_size, void* d_ws, size_t ws_size,
                              hipStream_t stream) {
    const float* z   = (const float*)d_in[0];   // [16,256,64,64]
    const float* emb = (const float*)d_in[1];   // [1024,256]
    int* out = (int*)d_out;                     // [65536] int32

    float* wsEE = (float*)d_ws;                 // 1024
    float* wsA  = wsEE + K_DIM;                 // 65536
    float* wsET = wsA + N_TOT;                  // 262144

    prep_kernel<<<772, 256, 0, stream>>>(z, emb, wsET, wsA, wsEE);
    vq_kernel<<<N_TOT / NW / 4, 256, 0, stream>>>(z, wsET, wsA, wsEE, out);
}

// Round 13
// 553.376 us; speedup vs baseline: 1.3433x; 1.2552x over previous
//
#include <hip/hip_runtime.h>

// VQ argmin: exact bit-level emulation of numpy fp32 reference:
//   A  = np.sum(flat*flat, axis=1)     (numpy pairwise-sum tree, fp32)
//   M2 = (2*flat) @ emb.T              (BLAS: sequential fp32 fma chain over d)
//   dist = (A - M2) + ee;  argmin_k (first-min ties)
// z_e_x: [B=16, D=256, H=64, W=64] fp32; embedding: [K=1024, D=256] fp32
// out: int32 [65536]
//
// R15 (resubmit; R12's bench was an infra failure -- container acquisition,
// no kernel signal). Fix R13/R14's measured per-row load serialization.
// Model (fits both rounds): per d-group the wave runs [issue loads, wait
// L~300cy, FMA], duty = FMA/(FMA+L) -> R13 predicted 730us (698 measured),
// R14's 4 waves/SIMD stall in lockstep (SGPR=96: ~2-3 z rows in flight).
// Changes vs R14:
//  - KL=4: lane owns 4 k's (k = kt*256 + q*64 + lane). FMA per z-row 16->64;
//    a 2-row compute half = 256cy >= L -> full cover with ping-pong.
//  - explicit 2-row ping-pong buffers for BOTH er (VGPR) and z (SGPR via
//    uniform-address loads), R3's proven za/zb pattern: prefetch half h+1,
//    compute half h. z: 1 s_load_dwordx16 per row, 4 rows in flight.
//  - acc[16][4]=64 VGPR; total ~120 -> proven (256,4)/128 budget, grid
//    1024 blocks = exactly 4/CU, single round.
// er traffic stays 4GB L2 (~13TB/s at target dur, comfortable); z traffic
// unchanged. Exact: per-(n,k) fmaf chain d ascending unchanged; dist =
// (An-acc)+ee; per-lane k ascending + strict-< + u64 (distbits,k) butterfly
// -> first-min ties (verified R13/R14, absmax=0). Prep kernel unchanged.

#define D_DIM  256
#define K_DIM  1024
#define HW     4096
#define N_TOT  65536
#define NW     16                 // n's per wave
#define KL     4                  // k's per lane
#define F32MAX 3.402823466e38f

// ---- fused prep: [0,256) et transpose | [256,768) A | [768,772) ee

__global__ void prep_kernel(const float* __restrict__ z, const float* __restrict__ e,
                            float* __restrict__ eT, float* __restrict__ A,
                            float* __restrict__ ee) {
#pragma clang fp contract(off)
    const int bid = blockIdx.x;
    const int t   = threadIdx.x;

    if (bid < 256) {
        // ---- transpose + fold the exact x2: eT[d][k] = 2*emb[k][d]
        __shared__ float tl[32][33];
        const int k0 = (bid & 31) * 32;
        const int d0 = (bid >> 5) * 32;
        const int tx = t & 31;
        const int ty = t >> 5;          // 0..7
        #pragma unroll
        for (int i = 0; i < 32; i += 8)
            tl[ty + i][tx] = 2.0f * e[(size_t)(k0 + ty + i) * D_DIM + d0 + tx];
        __syncthreads();
        #pragma unroll
        for (int i = 0; i < 32; i += 8)
            eT[(size_t)(d0 + ty + i) * K_DIM + k0 + tx] = tl[tx][ty + i];
    } else if (bid < 768) {
        // ---- A = numpy pairwise ||z_n||^2: 2 threads/n, one 128-half each
        // (independent 8-acc chains; total = s0 + s1). Bitwise-exact.
        const int tt = (bid - 256) * 256 + t;    // 0 .. 2*N_TOT-1
        const int n  = tt >> 1;
        const int h  = tt & 1;
        const int b  = n >> 12;
        const int hw = n & (HW - 1);
        const float* base = z + (size_t)b * D_DIM * HW + hw + (size_t)(h * 128) * HW;
        float r[8];
        #pragma unroll
        for (int j = 0; j < 8; ++j) { float v = base[(size_t)j * HW]; r[j] = v * v; }
        #pragma unroll
        for (int i = 8; i < 128; i += 8) {
            #pragma unroll
            for (int j = 0; j < 8; ++j) {
                float v = base[(size_t)(i + j) * HW];
                r[j] = r[j] + v * v;
            }
        }
        float s = ((r[0] + r[1]) + (r[2] + r[3])) + ((r[4] + r[5]) + (r[6] + r[7]));
        float other = __shfl_xor(s, 1);
        if (h == 0) A[n] = s + other;
    } else {
        // ---- ee = numpy pairwise ||e_k||^2 (two 128-halves of 8 accs)
        const int k = (bid - 768) * 256 + t;
        const float* row = e + (size_t)k * D_DIM;
        float total = 0.0f;
        #pragma unroll
        for (int h = 0; h < 2; ++h) {
            const float* a = row + h * 128;
            float r[8];
            #pragma unroll
            for (int j = 0; j < 8; ++j) { float v = a[j]; r[j] = v * v; }
            #pragma unroll
            for (int i = 8; i < 128; i += 8) {
                #pragma unroll
                for (int j = 0; j < 8; ++j) { float v = a[i + j]; r[j] = r[j] + v * v; }
            }
            float s = ((r[0] + r[1]) + (r[2] + r[3])) + ((r[4] + r[5]) + (r[6] + r[7]));
            total = (h == 0) ? s : (total + s);
        }
        ee[k] = total;
    }
}

// ---- main: wave owns 16 consecutive n (one b; z rows 64B-contiguous,
// wave-uniform -> s_load_dwordx16) x 256 k per supertile (4 per lane).
// Per d-row: 4 coalesced er loads (1KB, all useful) + 1 uniform z s_load
// (64B, all useful) + 64 v_fmac. 2-row halves, ping-pong prefetch.

__launch_bounds__(256, 4)
__global__ void vq_kernel(const float* __restrict__ z, const float* __restrict__ eT,
                          const float* __restrict__ A, const float* __restrict__ ee,
                          int* __restrict__ out) {
#pragma clang fp contract(off)
    const int lane = threadIdx.x & 63;
    const int wid  = __builtin_amdgcn_readfirstlane(threadIdx.x >> 6);
    const int gw   = blockIdx.x * 4 + wid;       // 0..1023, wave-uniform
    const int n0   = gw * NW;
    const int b    = n0 >> 12;                   // NW | 4096: never spans b
    const int hw0  = n0 & (HW - 1);
    const float* __restrict__ zrow = z + (size_t)b * D_DIM * HW + hw0;

    // A[n0..n0+15]: wave-uniform -> SGPR
    float An[NW];
    #pragma unroll
    for (int i = 0; i < NW; ++i) An[i] = A[n0 + i];

    unsigned int bkey[NW], bk[NW];
    #pragma unroll
    for (int i = 0; i < NW; ++i) { bkey[i] = 0xFFFFFFFFu; bk[i] = 0u; }

    #pragma unroll 1
    for (int kt = 0; kt < K_DIM / (64 * KL); ++kt) {   // 4 supertiles
        const int kb = kt * 64 * KL;
        const float* __restrict__ ep = eT + kb + lane;   // per-lane k base

        float acc[NW][KL];
        #pragma unroll
        for (int i = 0; i < NW; ++i)
            #pragma unroll
            for (int q = 0; q < KL; ++q) acc[i][q] = 0.0f;

        // ping-pong buffers: er in VGPR, z wave-uniform -> SGPR
        float ea[2][KL], eb[2][KL];
        float za[2][NW], zb[2][NW];
        // prime rows 0,1
        #pragma unroll
        for (int r = 0; r < 2; ++r) {
            #pragma unroll
            for (int q = 0; q < KL; ++q)
                ea[r][q] = ep[(size_t)r * K_DIM + q * 64];
            #pragma unroll
            for (int i = 0; i < NW; ++i)
                za[r][i] = zrow[(size_t)r * HW + i];
        }

        #pragma unroll 1
        for (int d = 0; d < D_DIM; d += 4) {
            // prefetch rows d+2, d+3
            #pragma unroll
            for (int r = 0; r < 2; ++r) {
                #pragma unroll
                for (int q = 0; q < KL; ++q)
                    eb[r][q] = ep[(size_t)(d + 2 + r) * K_DIM + q * 64];
                #pragma unroll
                for (int i = 0; i < NW; ++i)
                    zb[r][i] = zrow[(size_t)(d + 2 + r) * HW + i];
            }
            // compute rows d, d+1 (d ascending: exact per-(n,k) chain)
            #pragma unroll
            for (int r = 0; r < 2; ++r)
                #pragma unroll
                for (int i = 0; i < NW; ++i) {
                    const float zv = za[r][i];
                    #pragma unroll
                    for (int q = 0; q < KL; ++q)
                        acc[i][q] = fmaf(zv, ea[r][q], acc[i][q]);
                }
            // prefetch rows d+4, d+5 (mask-wrap keeps tail in-bounds; the
            // wrapped values are dead -- each kt re-primes)
            #pragma unroll
            for (int r = 0; r < 2; ++r) {
                const int dn = (d + 4 + r) & (D_DIM - 1);
                #pragma unroll
                for (int q = 0; q < KL; ++q)
                    ea[r][q] = ep[(size_t)dn * K_DIM + q * 64];
                #pragma unroll
                for (int i = 0; i < NW; ++i)
                    za[r][i] = zrow[(size_t)dn * HW + i];
            }
            // compute rows d+2, d+3
            #pragma unroll
            for (int r = 0; r < 2; ++r)
                #pragma unroll
                for (int i = 0; i < NW; ++i) {
                    const float zv = zb[r][i];
                    #pragma unroll
                    for (int q = 0; q < KL; ++q)
                        acc[i][q] = fmaf(zv, eb[r][q], acc[i][q]);
                }
        }

        // fold supertile into running best: q ascending -> k ascending per
        // lane; strict < keeps the earliest (lowest) k.
        #pragma unroll
        for (int q = 0; q < KL; ++q) {
            const int kq = kb + q * 64 + lane;
            const float eev = ee[kq];
            #pragma unroll
            for (int i = 0; i < NW; ++i) {
                const float dist = (An[i] - acc[i][q]) + eev;
                unsigned int d32 = __float_as_uint(dist);
                d32 ^= (unsigned int)((int)d32 >> 31) | 0x80000000u;  // total order
                if (d32 < bkey[i]) { bkey[i] = d32; bk[i] = (unsigned int)kq; }
            }
        }
    }

    // cross-lane exact first-min: u64 (key, k) butterfly min over 64 lanes;
    // equal keys resolve to the lowest k. One wave per n -> plain store.
    #pragma unroll
    for (int i = 0; i < NW; ++i) {
        unsigned long long key =
            ((unsigned long long)bkey[i] << 32) | (unsigned long long)bk[i];
        #pragma unroll
        for (int m = 1; m < 64; m <<= 1) {
            unsigned long long o = __shfl_xor(key, m, 64);
            if (o < key) key = o;
        }
        if (lane == 0) out[n0 + i] = (int)(key & 0xFFFFFFFFull);
    }
}

extern "C" void kernel_launch(void* const* d_in, const int* in_sizes, int n_in,
                              void* d_out, int out_size, void* d_ws, size_t ws_size,
                              hipStream_t stream) {
    const float* z   = (const float*)d_in[0];   // [16,256,64,64]
    const float* emb = (const float*)d_in[1];   // [1024,256]
    int* out = (int*)d_out;                     // [65536] int32

    float* wsEE = (float*)d_ws;                 // 1024
    float* wsA  = wsEE + K_DIM;                 // 65536
    float* wsET = wsA + N_TOT;                  // 262144

    prep_kernel<<<772, 256, 0, stream>>>(z, emb, wsET, wsA, wsEE);
    vq_kernel<<<N_TOT / NW / 4, 256, 0, stream>>>(z, wsET, wsA, wsEE, out);
}

// Round 14
// 465.067 us; speedup vs baseline: 1.5983x; 1.1899x over previous
//
#include <hip/hip_runtime.h>

// VQ argmin: exact bit-level emulation of numpy fp32 reference:
//   A  = np.sum(flat*flat, axis=1)     (numpy pairwise-sum tree, fp32)
//   M2 = (2*flat) @ emb.T              (BLAS: sequential fp32 fma chain over d)
//   dist = (A - M2) + ee;  argmin_k (first-min ties)
// z_e_x: [B=16, D=256, H=64, W=64] fp32; embedding: [K=1024, D=256] fp32
// out: int32 [65536]
//
// R16: R15 minus the spill. R15's WRITE_SIZE=125MB proved the explicit
// za/zb arrays did NOT scalarize -> 64 extra VGPRs -> scratch. R14 proved
// the direct-consumption form DOES scalarize (WRITE 256B, SGPR=96,
// s_load_dwordx16 per z row). R16 = R15's KL=4 + er 2-row ping-pong
// (16 VGPR), with z read DIRECTLY in the fmac loop (R14 form, no arrays).
// Budget: acc[16][4]=64 + er 16 + best 32 + temps ~8 = ~120 VGPR <= 128
// at the proven (256,4) point; z rows live in SGPRs via compiler s_load.
// Per 4-row iter: 256 fmac (512cy) vs ~200cy head latency -> duty ~0.75,
// x4 waves -> SIMD saturated. er L2 traffic 4GB (32 B/cy/CU < ~56 limit).
// Exact: per-(n,k) fmaf chain d ascending (rows via ea then eb, both
// ascending); dist=(An-acc)+ee; supertile/q/lane k ascending + strict-< +
// u64 (distbits,k) butterfly = first-min ties (absmax=0 in R13/R14/R15).
// Prep kernel unchanged (et+A+ee fused, verified).

#define D_DIM  256
#define K_DIM  1024
#define HW     4096
#define N_TOT  65536
#define NW     16                 // n's per wave
#define KL     4                  // k's per lane
#define F32MAX 3.402823466e38f

// ---- fused prep: [0,256) et transpose | [256,768) A | [768,772) ee

__global__ void prep_kernel(const float* __restrict__ z, const float* __restrict__ e,
                            float* __restrict__ eT, float* __restrict__ A,
                            float* __restrict__ ee) {
#pragma clang fp contract(off)
    const int bid = blockIdx.x;
    const int t   = threadIdx.x;

    if (bid < 256) {
        // ---- transpose + fold the exact x2: eT[d][k] = 2*emb[k][d]
        __shared__ float tl[32][33];
        const int k0 = (bid & 31) * 32;
        const int d0 = (bid >> 5) * 32;
        const int tx = t & 31;
        const int ty = t >> 5;          // 0..7
        #pragma unroll
        for (int i = 0; i < 32; i += 8)
            tl[ty + i][tx] = 2.0f * e[(size_t)(k0 + ty + i) * D_DIM + d0 + tx];
        __syncthreads();
        #pragma unroll
        for (int i = 0; i < 32; i += 8)
            eT[(size_t)(d0 + ty + i) * K_DIM + k0 + tx] = tl[tx][ty + i];
    } else if (bid < 768) {
        // ---- A = numpy pairwise ||z_n||^2: 2 threads/n, one 128-half each
        // (independent 8-acc chains; total = s0 + s1). Bitwise-exact.
        const int tt = (bid - 256) * 256 + t;    // 0 .. 2*N_TOT-1
        const int n  = tt >> 1;
        const int h  = tt & 1;
        const int b  = n >> 12;
        const int hw = n & (HW - 1);
        const float* base = z + (size_t)b * D_DIM * HW + hw + (size_t)(h * 128) * HW;
        float r[8];
        #pragma unroll
        for (int j = 0; j < 8; ++j) { float v = base[(size_t)j * HW]; r[j] = v * v; }
        #pragma unroll
        for (int i = 8; i < 128; i += 8) {
            #pragma unroll
            for (int j = 0; j < 8; ++j) {
                float v = base[(size_t)(i + j) * HW];
                r[j] = r[j] + v * v;
            }
        }
        float s = ((r[0] + r[1]) + (r[2] + r[3])) + ((r[4] + r[5]) + (r[6] + r[7]));
        float other = __shfl_xor(s, 1);
        if (h == 0) A[n] = s + other;
    } else {
        // ---- ee = numpy pairwise ||e_k||^2 (two 128-halves of 8 accs)
        const int k = (bid - 768) * 256 + t;
        const float* row = e + (size_t)k * D_DIM;
        float total = 0.0f;
        #pragma unroll
        for (int h = 0; h < 2; ++h) {
            const float* a = row + h * 128;
            float r[8];
            #pragma unroll
            for (int j = 0; j < 8; ++j) { float v = a[j]; r[j] = v * v; }
            #pragma unroll
            for (int i = 8; i < 128; i += 8) {
                #pragma unroll
                for (int j = 0; j < 8; ++j) { float v = a[i + j]; r[j] = r[j] + v * v; }
            }
            float s = ((r[0] + r[1]) + (r[2] + r[3])) + ((r[4] + r[5]) + (r[6] + r[7]));
            total = (h == 0) ? s : (total + s);
        }
        ee[k] = total;
    }
}

// ---- main: wave owns 16 consecutive n (one b; z row = 64B contiguous,
// wave-uniform address -> compiler s_load_dwordx16) x 256 k per supertile
// (4 per lane, stride 64). er: 2-row VGPR ping-pong of 4 coalesced loads
// per row. Per 4-row iter: 16 er loads + 4 z s_loads + 256 v_fmac.

__launch_bounds__(256, 4)
__global__ void vq_kernel(const float* __restrict__ z, const float* __restrict__ eT,
                          const float* __restrict__ A, const float* __restrict__ ee,
                          int* __restrict__ out) {
#pragma clang fp contract(off)
    const int lane = threadIdx.x & 63;
    const int wid  = __builtin_amdgcn_readfirstlane(threadIdx.x >> 6);
    const int gw   = blockIdx.x * 4 + wid;       // 0..1023, wave-uniform
    const int n0   = gw * NW;
    const int b    = n0 >> 12;                   // NW | 4096: never spans b
    const int hw0  = n0 & (HW - 1);
    const float* __restrict__ zrow = z + (size_t)b * D_DIM * HW + hw0;

    // A[n0..n0+15]: wave-uniform -> SGPR
    float An[NW];
    #pragma unroll
    for (int i = 0; i < NW; ++i) An[i] = A[n0 + i];

    unsigned int bkey[NW], bk[NW];
    #pragma unroll
    for (int i = 0; i < NW; ++i) { bkey[i] = 0xFFFFFFFFu; bk[i] = 0u; }

    #pragma unroll 1
    for (int kt = 0; kt < K_DIM / (64 * KL); ++kt) {   // 4 supertiles
        const int kb = kt * 64 * KL;
        const float* __restrict__ ep = eT + kb + lane;   // per-lane k base

        float acc[NW][KL];
        #pragma unroll
        for (int i = 0; i < NW; ++i)
            #pragma unroll
            for (int q = 0; q < KL; ++q) acc[i][q] = 0.0f;

        // er ping-pong buffers only (16 VGPR); z is consumed directly
        // (R14-proven scalarization; NO arrays -> no spill).
        float ea[2][KL], eb[2][KL];
        #pragma unroll
        for (int r = 0; r < 2; ++r)
            #pragma unroll
            for (int q = 0; q < KL; ++q)
                ea[r][q] = ep[(size_t)r * K_DIM + q * 64];

        #pragma unroll 1
        for (int d = 0; d < D_DIM; d += 4) {
            // phase A: prefetch er rows d+2,d+3; compute rows d,d+1
            #pragma unroll
            for (int r = 0; r < 2; ++r)
                #pragma unroll
                for (int q = 0; q < KL; ++q)
                    eb[r][q] = ep[(size_t)(d + 2 + r) * K_DIM + q * 64];
            #pragma unroll
            for (int r = 0; r < 2; ++r) {
                const float* __restrict__ zr = zrow + (size_t)(d + r) * HW;
                #pragma unroll
                for (int i = 0; i < NW; ++i) {
                    const float zv = zr[i];          // uniform -> s_load
                    #pragma unroll
                    for (int q = 0; q < KL; ++q)
                        acc[i][q] = fmaf(zv, ea[r][q], acc[i][q]);
                }
            }
            // phase B: prefetch er rows d+4,d+5 (mask-wrap: tail values
            // dead, re-primed next supertile); compute rows d+2,d+3
            #pragma unroll
            for (int r = 0; r < 2; ++r) {
                const int dn = (d + 4 + r) & (D_DIM - 1);
                #pragma unroll
                for (int q = 0; q < KL; ++q)
                    ea[r][q] = ep[(size_t)dn * K_DIM + q * 64];
            }
            #pragma unroll
            for (int r = 0; r < 2; ++r) {
                const float* __restrict__ zr = zrow + (size_t)(d + 2 + r) * HW;
                #pragma unroll
                for (int i = 0; i < NW; ++i) {
                    const float zv = zr[i];          // uniform -> s_load
                    #pragma unroll
                    for (int q = 0; q < KL; ++q)
                        acc[i][q] = fmaf(zv, eb[r][q], acc[i][q]);
                }
            }
        }

        // fold supertile into running best: q ascending -> k ascending per
        // lane; strict < keeps the earliest (lowest) k.
        #pragma unroll
        for (int q = 0; q < KL; ++q) {
            const int kq = kb + q * 64 + lane;
            const float eev = ee[kq];
            #pragma unroll
            for (int i = 0; i < NW; ++i) {
                const float dist = (An[i] - acc[i][q]) + eev;
                unsigned int d32 = __float_as_uint(dist);
                d32 ^= (unsigned int)((int)d32 >> 31) | 0x80000000u;  // total order
                if (d32 < bkey[i]) { bkey[i] = d32; bk[i] = (unsigned int)kq; }
            }
        }
    }

    // cross-lane exact first-min: u64 (key, k) butterfly min over 64 lanes;
    // equal keys resolve to the lowest k. One wave per n -> plain store.
    #pragma unroll
    for (int i = 0; i < NW; ++i) {
        unsigned long long key =
            ((unsigned long long)bkey[i] << 32) | (unsigned long long)bk[i];
        #pragma unroll
        for (int m = 1; m < 64; m <<= 1) {
            unsigned long long o = __shfl_xor(key, m, 64);
            if (o < key) key = o;
        }
        if (lane == 0) out[n0 + i] = (int)(key & 0xFFFFFFFFull);
    }
}

extern "C" void kernel_launch(void* const* d_in, const int* in_sizes, int n_in,
                              void* d_out, int out_size, void* d_ws, size_t ws_size,
                              hipStream_t stream) {
    const float* z   = (const float*)d_in[0];   // [16,256,64,64]
    const float* emb = (const float*)d_in[1];   // [1024,256]
    int* out = (int*)d_out;                     // [65536] int32

    float* wsEE = (float*)d_ws;                 // 1024
    float* wsA  = wsEE + K_DIM;                 // 65536
    float* wsET = wsA + N_TOT;                  // 262144

    prep_kernel<<<772, 256, 0, stream>>>(z, emb, wsET, wsA, wsEE);
    vq_kernel<<<N_TOT / NW / 4, 256, 0, stream>>>(z, wsET, wsA, wsEE, out);
}